// Round 1
// baseline (792.994 us; speedup 1.0000x reference)
//
#include <hip/hip_runtime.h>
#include <math.h>

// Preisach hysteresis via backward-record scan + 2D prefix-sum density table.
//
// Hysteron (beta_i, alpha_j), i<=j, on L=200 levels xs[0..L-1] (taken from
// mesh_points so float comparisons match the reference exactly).
// C[a][b] = sum_{j<a, i<b, i<=j} softplus(raw_density[p(i,j)]), a,b in [0,L].
// packed index p(i,j) = L*i - i*(i-1)/2 + (j-i).

__device__ __forceinline__ float softplus_f(float x) {
    // jax.nn.softplus = logaddexp(x, 0) = max(x,0) + log1p(exp(-|x|))
    return fmaxf(x, 0.0f) + log1pf(expf(-fabsf(x)));
}

__global__ void build_prefix_kernel(const float* __restrict__ raw,
                                    float* __restrict__ C, int L) {
    const int tid = threadIdx.x;
    const int stride = blockDim.x;
    const int W = L + 1;

    // Phase A: row a = j+1 holds R[j][b] = sum_{i < min(b, j+1)} dens(i, j)
    for (int j = tid; j < L; j += stride) {
        float r = 0.0f;
        int p = j;  // p(0, j)
        float* row = C + (size_t)(j + 1) * W;
        row[0] = 0.0f;
        for (int b = 1; b <= L; ++b) {
            int i = b - 1;
            if (i <= j) {
                r += softplus_f(raw[p]);
                p += (L - 1) - i;  // p(i+1,j) - p(i,j)
            }
            row[b] = r;
        }
    }
    // row a = 0 is zero
    for (int b = tid; b < W; b += stride) C[b] = 0.0f;
    __syncthreads();

    // Phase B: column prefix over a (coalesced across b)
    for (int b = tid; b < W; b += stride) {
        float run = 0.0f;
        for (int a = 1; a <= L; ++a) {
            run += C[(size_t)a * W + b];
            C[(size_t)a * W + b] = run;
        }
    }
}

__global__ void hysteresis_kernel(const float* __restrict__ h,
                                  const float* __restrict__ mesh,
                                  const float* __restrict__ C,
                                  const float* __restrict__ scale,
                                  const float* __restrict__ offset,
                                  float* __restrict__ out,
                                  int T, int L, int n) {
    extern __shared__ float smem[];
    float* lh = smem;       // T floats
    float* xs = smem + T;   // L floats

    const int tid = threadIdx.x;
    for (int k = tid; k < T; k += blockDim.x) lh[k] = h[k];
    // xs[j] = alpha of point j (first row of the triangle has beta = xs[0])
    for (int k = tid; k < L; k += blockDim.x) xs[k] = mesh[2 * k + 1];
    __syncthreads();

    const int t = blockIdx.x * blockDim.x + tid;
    if (t >= T) return;

    const int W = L + 1;
    float u_max = -1.0f;   // highest up-level seen (backward)
    float d_min = 2.0f;    // lowest down-level seen (backward)
    int Acov = 0;          // #{xs <= u_max}  (alpha levels determined +1-side)
    int Bcov = L;          // #{xs <  d_min}  (beta levels NOT yet determined by downs)
    float splus = 0.0f, sminus = 0.0f;

    float hv = lh[t];
    int i = t;
    while (true) {
        float hp = (i > 0) ? lh[i - 1] : 0.0f;
        if (hv > hp) {                       // up-move to level hv
            if (hv > u_max) {
                u_max = hv;
                int lo = Acov, hi = L;       // Anew = #{xs <= hv}, >= Acov
                while (lo < hi) {
                    int mid = (lo + hi) >> 1;
                    if (xs[mid] <= hv) lo = mid + 1; else hi = mid;
                }
                if (lo > Acov) {
                    splus += C[(size_t)lo * W + Bcov] - C[(size_t)Acov * W + Bcov];
                    Acov = lo;
                }
            }
        } else if (hv < hp) {                // down-move to level hv
            if (hv < d_min) {
                d_min = hv;
                int lo = 0, hi = Bcov;       // Bnew = #{xs < hv}, <= Bcov
                while (lo < hi) {
                    int mid = (lo + hi) >> 1;
                    if (xs[mid] < hv) lo = mid + 1; else hi = mid;
                }
                if (lo < Bcov) {
                    sminus += (C[(size_t)L * W + Bcov] - C[(size_t)L * W + lo])
                            - (C[(size_t)Acov * W + Bcov] - C[(size_t)Acov * W + lo]);
                    Bcov = lo;
                }
            }
        }
        if (i == 0) break;
        hv = hp;
        --i;
    }
    // remaining undetermined region keeps initial state -1
    sminus += C[(size_t)L * W + Bcov] - C[(size_t)Acov * W + Bcov];

    float m = (splus - sminus) / (float)n;
    out[t] = scale[0] * m + offset[0];
}

extern "C" void kernel_launch(void* const* d_in, const int* in_sizes, int n_in,
                              void* d_out, int out_size, void* d_ws, size_t ws_size,
                              hipStream_t stream) {
    const float* h      = (const float*)d_in[0];
    const float* mesh   = (const float*)d_in[1];
    const float* raw    = (const float*)d_in[2];
    const float* scale  = (const float*)d_in[3];
    const float* offset = (const float*)d_in[4];
    float* out = (float*)d_out;

    const int T = in_sizes[0];
    const int n = in_sizes[2];
    // n = L*(L+1)/2
    const int L = (int)((sqrt(8.0 * (double)n + 1.0) - 1.0) / 2.0 + 0.5);

    float* C = (float*)d_ws;  // (L+1)*(L+1) floats ≈ 162 KB

    hipLaunchKernelGGL(build_prefix_kernel, dim3(1), dim3(256), 0, stream,
                       raw, C, L);

    const int block = 256;
    const int grid = (T + block - 1) / block;
    const size_t shmem = (size_t)(T + L) * sizeof(float);
    hipLaunchKernelGGL(hysteresis_kernel, dim3(grid), dim3(block), shmem, stream,
                       h, mesh, C, scale, offset, out, T, L, n);
}

// Round 2
// 60.317 us; speedup vs baseline: 13.1471x; 13.1471x over previous
//
#include <hip/hip_runtime.h>
#include <math.h>

// Preisach hysteresis, wave-cooperative backward-record scan + 2D prefix table.
//
// Hysteron (beta_i, alpha_j), i<=j, L=200 levels xs[] (taken from mesh_points
// so float comparisons match the reference bit-exactly).
// C[a][b] = sum_{alpha_idx<a, beta_idx<b, beta<=alpha} softplus(raw[p(i,j)]),
// a,b in [0,L].  p(i,j) = L*i - i*(i-1)/2 + (j-i).
//
// Backward-record decomposition: scanning i = t..0, maintain up-record u_max /
// down-record d_min. New up record v: +1 rectangle alpha_idx [Acov,lo) x
// beta_idx [0,Bcov). New down record v: -1 rectangle beta_idx [lo,Bcov) x
// alpha_idx [Acov,L). Leftover region keeps initial -1.

__device__ __forceinline__ float softplus_f(float x) {
    return fmaxf(x, 0.0f) + log1pf(expf(-fabsf(x)));
}

// ---------- prefix table build: rows (wave per row) ----------
__global__ void build_rows_kernel(const float* __restrict__ raw,
                                  float* __restrict__ C, int L) {
    const int lane = threadIdx.x & 63;
    const int wid  = threadIdx.x >> 6;
    const int j = blockIdx.x * (blockDim.x >> 6) + wid;  // row (alpha index)
    const int W = L + 1;
    if (j >= L) return;

    float* row = C + (size_t)(j + 1) * W;
    float carry = 0.0f;
    for (int k = 0; 64 * k <= j; ++k) {
        int i = lane + 64 * k;           // beta index
        float d = 0.0f;
        if (i <= j) {
            int p = L * i - (i * (i - 1)) / 2 + (j - i);
            d = softplus_f(raw[p]);
        }
        // wave inclusive scan
        float x = d;
        for (int off = 1; off < 64; off <<= 1) {
            float tv = __shfl_up(x, off);
            if (lane >= off) x += tv;
        }
        float incl = x + carry;
        if (i <= j) row[i + 1] = incl;
        carry += __shfl(x, 63);
    }
    const float total = carry;
    for (int b = j + 2 + lane; b <= L; b += 64) row[b] = total;
    if (lane == 0) row[0] = 0.0f;
    if (j == 0) {
        for (int b = lane; b <= L; b += 64) C[b] = 0.0f;  // row a=0
    }
}

// ---------- prefix table build: column scan over a ----------
__global__ void build_cols_kernel(float* __restrict__ C, int L) {
    const int b = blockIdx.x * blockDim.x + threadIdx.x;
    const int W = L + 1;
    if (b >= W) return;
    float* p = C + b;
    float run = 0.0f;
    int a = 1;
    for (; a + 3 <= L; a += 4) {
        float v0 = p[(size_t)(a    ) * W];
        float v1 = p[(size_t)(a + 1) * W];
        float v2 = p[(size_t)(a + 2) * W];
        float v3 = p[(size_t)(a + 3) * W];
        run += v0; p[(size_t)(a    ) * W] = run;
        run += v1; p[(size_t)(a + 1) * W] = run;
        run += v2; p[(size_t)(a + 2) * W] = run;
        run += v3; p[(size_t)(a + 3) * W] = run;
    }
    for (; a <= L; ++a) {
        run += p[(size_t)a * W];
        p[(size_t)a * W] = run;
    }
}

// ---------- main: one wave per output t ----------
__device__ __forceinline__ int wave_count_le(float v, const float xsr[4]) {
    int c = (xsr[0] <= v) + (xsr[1] <= v) + (xsr[2] <= v) + (xsr[3] <= v);
    for (int off = 1; off < 64; off <<= 1) c += __shfl_xor(c, off);
    return c;
}
__device__ __forceinline__ int wave_count_lt(float v, const float xsr[4]) {
    int c = (xsr[0] < v) + (xsr[1] < v) + (xsr[2] < v) + (xsr[3] < v);
    for (int off = 1; off < 64; off <<= 1) c += __shfl_xor(c, off);
    return c;
}

__global__ void hysteresis_kernel(const float* __restrict__ h,
                                  const float* __restrict__ mesh,
                                  const float* __restrict__ C,
                                  const float* __restrict__ scale,
                                  const float* __restrict__ offset,
                                  float* __restrict__ out,
                                  int T, int L, int n) {
    extern __shared__ float smem[];
    const int nc = (T + 63) >> 6;
    float* lh   = smem;          // T
    float* cmax = smem + T;      // nc
    float* cmin = cmax + nc;     // nc

    const int tid    = threadIdx.x;
    const int lane   = tid & 63;
    const int wid    = tid >> 6;
    const int nwaves = blockDim.x >> 6;

    // stage h (vectorized where possible)
    const int T4 = T >> 2;
    const float4* h4 = (const float4*)h;
    float4* lh4 = (float4*)lh;
    for (int idx = tid; idx < T4; idx += blockDim.x) lh4[idx] = h4[idx];
    for (int idx = T4 * 4 + tid; idx < T; idx += blockDim.x) lh[idx] = h[idx];

    // xs levels into registers: lane holds levels lane, lane+64, +128, +192
    float xsr[4];
#pragma unroll
    for (int k = 0; k < 4; ++k) {
        int j = lane + 64 * k;
        xsr[k] = (j < L) ? mesh[2 * j + 1] : 2.0f;  // 2.0 never matches (h in (0,1))
    }
    __syncthreads();

    // per-chunk max/min
    for (int c = wid; c < nc; c += nwaves) {
        int i = (c << 6) + lane;
        float v  = (i < T) ? lh[i] : lh[T - 1];
        float mx = v, mn = v;
        for (int off = 1; off < 64; off <<= 1) {
            mx = fmaxf(mx, __shfl_xor(mx, off));
            mn = fminf(mn, __shfl_xor(mn, off));
        }
        if (lane == 0) { cmax[c] = mx; cmin[c] = mn; }
    }
    __syncthreads();

    const int t = blockIdx.x * nwaves + wid;
    if (t >= T) return;

    const int W = L + 1;
    float u_max = -1.0f;
    float d_min = 2.0f;
    int Acov = 0;      // #{xs <= u_max}
    int Bcov = L;      // #{xs <  d_min}
    float splus = 0.0f, sminus = 0.0f;

    for (int c = t >> 6; c >= 0; --c) {
        // chunk can hold a record only if it exceeds a current record
        if (!(cmax[c] > u_max || cmin[c] < d_min)) continue;  // wave-uniform

        const int i = (c << 6) + lane;
        const float hv = lh[i];
        const float hp = (i > 0) ? lh[i - 1] : 0.0f;
        const bool valid = (i <= t);
        const bool isup = valid && (hv > hp);
        const bool isdn = valid && (hv < hp);

        unsigned long long mup = __ballot(isup && hv > u_max);
        unsigned long long mdn = __ballot(isdn && hv < d_min);
        unsigned long long m = mup | mdn;
        while (m) {
            const int rl = 63 - __builtin_clzll(m);   // largest i first
            const float v = __shfl(hv, rl);
            if ((mup >> rl) & 1ull) {
                u_max = v;
                int lo = wave_count_le(v, xsr);
                if (lo > Acov) {
                    splus += C[(size_t)lo * W + Bcov] - C[(size_t)Acov * W + Bcov];
                    Acov = lo;
                }
            } else {
                d_min = v;
                int lo = wave_count_lt(v, xsr);
                if (lo < Bcov) {
                    sminus += (C[(size_t)L * W + Bcov] - C[(size_t)L * W + lo])
                            - (C[(size_t)Acov * W + Bcov] - C[(size_t)Acov * W + lo]);
                    Bcov = lo;
                }
            }
            const unsigned long long below =
                (rl == 0) ? 0ull : ((1ull << rl) - 1ull);
            mup = __ballot(isup && hv > u_max) & below;
            mdn = __ballot(isdn && hv < d_min) & below;
            m = mup | mdn;
        }
        if (Acov >= L || Bcov <= 0) break;  // fully determined
    }
    // leftover region keeps initial -1
    sminus += C[(size_t)L * W + Bcov] - C[(size_t)Acov * W + Bcov];

    const float mval = (splus - sminus) / (float)n;
    if (lane == 0) out[t] = scale[0] * mval + offset[0];
}

extern "C" void kernel_launch(void* const* d_in, const int* in_sizes, int n_in,
                              void* d_out, int out_size, void* d_ws, size_t ws_size,
                              hipStream_t stream) {
    const float* h      = (const float*)d_in[0];
    const float* mesh   = (const float*)d_in[1];
    const float* raw    = (const float*)d_in[2];
    const float* scale  = (const float*)d_in[3];
    const float* offset = (const float*)d_in[4];
    float* out = (float*)d_out;

    const int T = in_sizes[0];
    const int n = in_sizes[2];
    const int L = (int)((sqrt(8.0 * (double)n + 1.0) - 1.0) / 2.0 + 0.5);
    const int W = L + 1;

    float* C = (float*)d_ws;  // W*W floats (~162 KB)

    // rows: one wave per row
    {
        const int block = 256;
        const int waves_per_block = block / 64;
        const int grid = (L + waves_per_block - 1) / waves_per_block;
        hipLaunchKernelGGL(build_rows_kernel, dim3(grid), dim3(block), 0, stream,
                           raw, C, L);
    }
    // columns: serial scan per column, unrolled
    {
        const int block = 64;
        const int grid = (W + block - 1) / block;
        hipLaunchKernelGGL(build_cols_kernel, dim3(grid), dim3(block), 0, stream,
                           C, L);
    }
    // main: one wave per t
    {
        const int block = 256;
        const int nwaves = block / 64;
        const int grid = (T + nwaves - 1) / nwaves;
        const int nc = (T + 63) / 64;
        const size_t shmem = (size_t)(T + 2 * nc) * sizeof(float);
        hipLaunchKernelGGL(hysteresis_kernel, dim3(grid), dim3(block), shmem,
                           stream, h, mesh, C, scale, offset, out, T, L, n);
    }
}